// Round 11
// baseline (967.370 us; speedup 1.0000x reference)
//
#include <hip/hip_runtime.h>
#include <math.h>

#define NITEM 100
#define CDIM 512
#define HW 4096
#define KTOP 10

typedef __attribute__((ext_vector_type(8))) short bf16x8;
typedef __attribute__((ext_vector_type(4))) float f32x4;

__device__ inline unsigned short bf16u(float f) {
  unsigned int u = __float_as_uint(f);
  u += 0x7fffu + ((u >> 16) & 1u);     // RNE
  return (unsigned short)(u >> 16);
}

// ---- setup: mpT[512 k][128 item] f32, zero-padded ----
__global__ void make_mpT(const float* __restrict__ mp, float* __restrict__ mpT) {
  int idx = blockIdx.x * 256 + threadIdx.x;   // 0..65535
  int k = idx >> 7, item = idx & 127;
  mpT[idx] = (item < NITEM) ? mp[item * CDIM + k] : 0.f;
}

// ---- K1: fp32 logits GEMM + in-register top-10 + renorm -> dense bf16 W [N][112] ----
// R6 shell (256 thr, waves_per_eu(3,3) = only proven spill-free mode) with both
// operands global_load_lds-staged and read as ds_read_b128 pairs:
// per kk per thread: 2 q-b128 (16-way bcast) + 2 m-b128 (4-way) + 64 FMA -> VALU-bound.
// Thread (trg=t>>4, tc=t&15): rows 8trg..8trg+7, items 8tc..8tc+7 (R8-proven selection).
// BK=16, both tiles double-buffered: LDS 32 KB -> 3 blocks/CU.
__global__ __launch_bounds__(256) __attribute__((amdgpu_waves_per_eu(3, 3)))
void logits_topk(
    const float* __restrict__ x, const float* __restrict__ mpT,
    unsigned short* __restrict__ Wd)
{
  __shared__ float qs[2][16 * 128];   // [buf][kk][row]   2 x 8 KB
  __shared__ float ms[2][16 * 128];   // [buf][kk][item]  2 x 8 KB

  const int t   = threadIdx.x;
  const int tc  = t & 15;
  const int trg = t >> 4;              // 0..15 -> rows 8trg..8trg+7
  const int n0  = blockIdx.x * 128;
  const int b   = n0 >> 12;
  const int sp0 = n0 & (HW - 1);
  const float* xb = x + (size_t)b * CDIM * HW + sp0;
  const int w = t >> 6, l = t & 63;    // wave id, lane id

  // both tiles: 8 KB = 8 wave-instrs of 1 KB; wave w instr i covers kk0=2*(4i+w), kk0+1
  auto issue_tile = [&](int kt, int buf) {
    const int k0 = kt * 16;
    #pragma unroll
    for (int i = 0; i < 2; ++i) {
      const int kk0 = 2 * (4 * i + w);               // wave-uniform
      const float* srcq = xb + (size_t)(k0 + kk0 + (l >> 5)) * HW + (l & 31) * 4;
      float* dstq = &qs[buf][kk0 * 128];             // + l*16B implicit
      __builtin_amdgcn_global_load_lds(
          (const __attribute__((address_space(1))) void*)srcq,
          (__attribute__((address_space(3))) void*)dstq, 16, 0, 0);
      const float* srcm = mpT + (size_t)(k0 + kk0 + (l >> 5)) * 128 + (l & 31) * 4;
      float* dstm = &ms[buf][kk0 * 128];
      __builtin_amdgcn_global_load_lds(
          (const __attribute__((address_space(1))) void*)srcm,
          (__attribute__((address_space(3))) void*)dstm, 16, 0, 0);
    }
  };

  float acc[8][8];
  #pragma unroll
  for (int r = 0; r < 8; ++r)
    #pragma unroll
    for (int j = 0; j < 8; ++j) acc[r][j] = 0.f;

  issue_tile(0, 0);                    // prologue

  int buf = 0;
  #pragma unroll 1
  for (int kt = 0; kt < 32; ++kt) {
    __syncthreads();                   // tile kt landed (vmcnt drained at barrier)
    if (kt < 31) issue_tile(kt + 1, buf ^ 1);   // in flight during compute below
    const float* qsb = qs[buf];
    const float* msb = ms[buf];
    #pragma unroll 2
    for (int kk = 0; kk < 16; ++kk) {
      const float* qr = qsb + kk * 128 + 8 * trg;
      const float* mr = msb + kk * 128 + 8 * tc;
      float4 qa = *(const float4*)(qr);
      float4 qb4 = *(const float4*)(qr + 4);
      float4 ma = *(const float4*)(mr);
      float4 mb = *(const float4*)(mr + 4);
      float qq[8] = {qa.x, qa.y, qa.z, qa.w, qb4.x, qb4.y, qb4.z, qb4.w};
      float mm[8] = {ma.x, ma.y, ma.z, ma.w, mb.x, mb.y, mb.z, mb.w};
      #pragma unroll
      for (int r = 0; r < 8; ++r)
        #pragma unroll
        for (int j = 0; j < 8; ++j)
          acc[r][j] = __builtin_fmaf(qq[r], mm[j], acc[r][j]);
    }
    buf ^= 1;
  }

  // ---- in-register softmax + top-10 + renorm per row (16-lane groups) ----
  // Item-blocked selection (R8-proven). FULLY unrolled, constant indices.
  const int baserow = n0 + 8 * trg;
  #pragma unroll
  for (int r = 0; r < 8; ++r) {
    float attv[KTOP]; int id[KTOP];
    float mx = 0.f, Z = 0.f;
    #pragma unroll
    for (int s = 0; s < KTOP; ++s) {
      float bv = -INFINITY; int bi = 0x7fffffff;
      #pragma unroll
      for (int jj = 0; jj < 8; ++jj) {
        bool valid = (8 * tc + jj) < NITEM;
        float v = valid ? acc[r][jj] : -INFINITY;
        if (v > bv) { bv = v; bi = 8 * tc + jj; }   // ascending idx: > keeps lowest
      }
      #pragma unroll
      for (int d = 1; d < 16; d <<= 1) {
        float ov = __shfl_xor(bv, d, 16);
        int   oi = __shfl_xor(bi, d, 16);
        if (ov > bv || (ov == bv && oi < bi)) { bv = ov; bi = oi; }
      }
      if (s == 0) {                    // global max known: compute Z on unmasked values
        mx = bv;
        float zp = 0.f;
        #pragma unroll
        for (int jj = 0; jj < 8; ++jj) {
          bool valid = (8 * tc + jj) < NITEM;
          zp += valid ? __expf(acc[r][jj] - mx) : 0.f;
        }
        #pragma unroll
        for (int d = 1; d < 16; d <<= 1) zp += __shfl_xor(zp, d, 16);
        Z = zp;
      }
      attv[s] = bv; id[s] = bi;
      // mask winner (predicated, constant indices)
      #pragma unroll
      for (int jj = 0; jj < 8; ++jj)
        if (bi == 8 * tc + jj) acc[r][jj] = -INFINITY;
    }
    float invZ = 1.f / Z;
    float p0 = invZ;                   // exp(attv0-mx)=1
    float s2 = 0.f, wv[KTOP];
    #pragma unroll
    for (int s = 0; s < KTOP; ++s) {
      float p = __expf(attv[s] - mx) * invZ;
      float e = __expf(p - p0);
      wv[s] = e; s2 += e;
    }
    float inv2 = 1.f / s2;
    unsigned short wb[KTOP];
    #pragma unroll
    for (int s = 0; s < KTOP; ++s) wb[s] = bf16u(wv[s] * inv2);
    // assemble W row: lane tc owns items 8tc..8tc+7 (one uint4), predicated selects
    unsigned int packed[4];
    #pragma unroll
    for (int q2 = 0; q2 < 4; ++q2) {
      unsigned int lo = 0u, hi = 0u;
      #pragma unroll
      for (int s = 0; s < KTOP; ++s) {
        lo = (id[s] == 8 * tc + 2 * q2)     ? (unsigned int)wb[s] : lo;
        hi = (id[s] == 8 * tc + 2 * q2 + 1) ? (unsigned int)wb[s] : hi;
      }
      packed[q2] = lo | (hi << 16);
    }
    if (tc < 14) {
      uint4 o; o.x = packed[0]; o.y = packed[1]; o.z = packed[2]; o.w = packed[3];
      *(uint4*)(Wd + (size_t)(baserow + r) * 112 + 8 * tc) = o;
    }
  }
}

// ---- K2: out^T = mp^T(bf16) x W^T(bf16) via MFMA; tiles 128c x 128n, K=128 ----
__global__ __launch_bounds__(256, 2) void recon(
    const float* __restrict__ mp, const unsigned short* __restrict__ Wd,
    float* __restrict__ out)
{
  __shared__ unsigned short Ash[128 * 136];  // mp^T bf16 [c][k], k-stride 136
  __shared__ unsigned short Bsh[128 * 136];  // W bf16 [n][k]
  const int t  = threadIdx.x;
  const int ct = blockIdx.x & 3, nt = blockIdx.x >> 2;
  const int c0 = ct * 128, n0 = nt * 128;
  const int b  = n0 >> 12, sp0 = n0 & (HW - 1);

  #pragma unroll
  for (int j = 0; j < 13; ++j) {
    int task = t + 256 * j;
    if (task < 3200) {
      int k = task >> 5, c4 = (task & 31) << 2;
      float4 v = *(const float4*)(mp + (size_t)k * CDIM + c0 + c4);
      Ash[(c4 + 0) * 136 + k] = bf16u(v.x);
      Ash[(c4 + 1) * 136 + k] = bf16u(v.y);
      Ash[(c4 + 2) * 136 + k] = bf16u(v.z);
      Ash[(c4 + 3) * 136 + k] = bf16u(v.w);
    }
  }
  {
    int c = t >> 1, hf = t & 1;
    unsigned int* A32 = (unsigned int*)Ash;
    #pragma unroll
    for (int j = 0; j < 9; ++j) { int k = 100 + 2 * (hf * 9 + j); A32[(c * 136 + k) >> 1] = 0u; }
  }
  {
    int n = t >> 1, hf = t & 1;
    #pragma unroll
    for (int j = 0; j < 7; ++j) {
      int f = hf * 7 + j;
      *(bf16x8*)(Bsh + n * 136 + 8 * f) = *(const bf16x8*)(Wd + (size_t)(n0 + n) * 112 + 8 * f);
    }
    unsigned int* B32 = (unsigned int*)Bsh;
    #pragma unroll
    for (int j = 0; j < 6; ++j) { int k = 112 + 2 * (hf * 6 + j); B32[(n * 136 + k) >> 1] = 0u; }
  }
  __syncthreads();

  const int w = t >> 6, l = t & 63;
  const int arow = l & 15, kg = l >> 4;
  f32x4 acc[2][8];
  #pragma unroll
  for (int cr = 0; cr < 2; ++cr)
    #pragma unroll
    for (int n = 0; n < 8; ++n) acc[cr][n] = (f32x4){0.f, 0.f, 0.f, 0.f};

  #pragma unroll
  for (int ks = 0; ks < 4; ++ks) {
    bf16x8 a0 = *(bf16x8*)(Ash + ((2 * w + 0) * 16 + arow) * 136 + ks * 32 + kg * 8);
    bf16x8 a1 = *(bf16x8*)(Ash + ((2 * w + 1) * 16 + arow) * 136 + ks * 32 + kg * 8);
    #pragma unroll
    for (int nn = 0; nn < 8; ++nn) {
      bf16x8 bb = *(bf16x8*)(Bsh + (nn * 16 + arow) * 136 + ks * 32 + kg * 8);
      acc[0][nn] = __builtin_amdgcn_mfma_f32_16x16x32_bf16(a0, bb, acc[0][nn], 0, 0, 0);
      acc[1][nn] = __builtin_amdgcn_mfma_f32_16x16x32_bf16(a1, bb, acc[1][nn], 0, 0, 0);
    }
  }

  float* ob = out + (size_t)b * CDIM * HW + sp0;
  #pragma unroll
  for (int cr = 0; cr < 2; ++cr) {
    #pragma unroll
    for (int nn = 0; nn < 8; ++nn) {
      int ncol = nn * 16 + arow;
      #pragma unroll
      for (int j = 0; j < 4; ++j) {
        int cc = c0 + (2 * w + cr) * 16 + kg * 4 + j;
        ob[(size_t)cc * HW + ncol] = acc[cr][nn][j];
      }
    }
  }
}

// ---- loss: mean |0.5 * off-diag gram| ----
__global__ void loss_partial(const float* __restrict__ mp, float* __restrict__ part)
{
  __shared__ float mi[CDIM];
  __shared__ float red[4];
  const int i = blockIdx.x;
  const int t = threadIdx.x;
  for (int k = t; k < CDIM; k += 256) mi[k] = mp[i * CDIM + k];
  __syncthreads();
  float v = 0.f;
  if (t < NITEM && t != i) {
    const float* mj = mp + t * CDIM;
    float d = 0.f;
    #pragma unroll 8
    for (int k = 0; k < CDIM; ++k) d += mi[k] * mj[k];
    v = fabsf(0.5f * d);
  }
  #pragma unroll
  for (int o = 32; o > 0; o >>= 1) v += __shfl_down(v, o, 64);
  if ((t & 63) == 0) red[t >> 6] = v;
  __syncthreads();
  if (t == 0) part[i] = red[0] + red[1] + red[2] + red[3];
}

__global__ void loss_final(const float* __restrict__ part, float* __restrict__ out_loss)
{
  if (threadIdx.x == 0) {
    float s = 0.f;
    for (int i = 0; i < NITEM; ++i) s += part[i];
    *out_loss = s / (float)(NITEM * NITEM);
  }
}

extern "C" void kernel_launch(void* const* d_in, const int* in_sizes, int n_in,
                              void* d_out, int out_size, void* d_ws, size_t ws_size,
                              hipStream_t stream) {
  const float* x  = (const float*)d_in[0];
  const float* mp = (const float*)d_in[1];
  float* out = (float*)d_out;
  unsigned short* Wd = (unsigned short*)d_ws;                    // 131072*112*2 = 29.36 MB
  float* part = (float*)((char*)d_ws + (size_t)131072 * 112 * 2);

  // mpT scratch lives in d_out tail (recon fully rewrites out afterwards)
  float* mpT = out + (size_t)60 * 1024 * 1024;                   // 512*128 floats = 256 KB

  make_mpT<<<256, 256, 0, stream>>>(mp, mpT);
  logits_topk<<<1024, 256, 0, stream>>>(x, mpT, Wd);
  recon<<<4096, 256, 0, stream>>>(mp, Wd, out);
  loss_partial<<<NITEM, 256, 0, stream>>>(mp, part);
  loss_final<<<1, 64, 0, stream>>>(part, out + (out_size - 1));
}

// Round 12
// 374.125 us; speedup vs baseline: 2.5857x; 2.5857x over previous
//
#include <hip/hip_runtime.h>
#include <math.h>

#define NITEM 100
#define CDIM 512
#define HW 4096
#define KTOP 10

typedef __attribute__((ext_vector_type(8))) short bf16x8;
typedef __attribute__((ext_vector_type(4))) float f32x4;

__device__ inline unsigned short bf16u(float f) {
  unsigned int u = __float_as_uint(f);
  u += 0x7fffu + ((u >> 16) & 1u);     // RNE
  return (unsigned short)(u >> 16);
}

// ---- K1: fp32 logits GEMM + in-register top-10 + renorm -> dense bf16 W [N][112] ----
// 256 threads, 128 rows/block. Thread (trg=t>>4, tc=t&15): rows 8trg..8trg+7,
// items tc+16j (j=0..6). Row-group = 16 lanes sharing trg (width-16 shuffles).
// q staged via global_load_lds (double-buffered); m reg-staged (scatter writes).
// amdgpu_waves_per_eu(3,3): proven spill-free allocation mode (VGPR=68, WRITE=Wd).
// acc ≤ 56 floats is the empirical no-spill envelope for 256-thread blocks.
__global__ __launch_bounds__(256) __attribute__((amdgpu_waves_per_eu(3, 3)))
void logits_topk(
    const float* __restrict__ x, const float* __restrict__ mp,
    unsigned short* __restrict__ Wd)
{
  __shared__ float qs[2][32 * 128];   // [buf][kk][row]  2 x 16 KB
  __shared__ float ms[32 * 128];      // [kk][item]      16 KB

  const int t   = threadIdx.x;
  const int tc  = t & 15;
  const int trg = t >> 4;              // 0..15
  const int n0  = blockIdx.x * 128;
  const int b   = n0 >> 12;
  const int sp0 = n0 & (HW - 1);
  const float* xb = x + (size_t)b * CDIM * HW + sp0;

  const int w = t >> 6, l = t & 63;    // wave id, lane id
  const int item = t & 127;
  const int half = t >> 7;             // kk range 16*half..16*half+15
  const float* mrow = mp + (size_t)(item < NITEM ? item : 0) * CDIM + 16 * half;

  // q tile load: wave w covers kk = 8w..8w+7; per instr i: kk = 8w+2i+(l>>5), row = (l&31)*4
  auto issue_q = [&](int kt, int buf) {
    const int k0 = kt * 32;
    #pragma unroll
    for (int i = 0; i < 4; ++i) {
      const float* src = xb + (size_t)(k0 + 8 * w + 2 * i + (l >> 5)) * HW + (l & 31) * 4;
      float* dst = &qs[buf][(8 * w + 2 * i) * 128];        // wave-uniform base
      __builtin_amdgcn_global_load_lds(
          (const __attribute__((address_space(1))) void*)src,
          (__attribute__((address_space(3))) void*)dst, 16, 0, 0);
    }
  };

  float acc[8][7];
  #pragma unroll
  for (int r = 0; r < 8; ++r)
    #pragma unroll
    for (int j = 0; j < 7; ++j) acc[r][j] = 0.f;

  // prologue: tile 0
  issue_q(0, 0);
  float4 mv4[4];
  #pragma unroll
  for (int u = 0; u < 4; ++u) mv4[u] = *(const float4*)(mrow + 4 * u);

  int buf = 0;
  #pragma unroll 1
  for (int kt = 0; kt < 16; ++kt) {
    // store staged m registers -> LDS (scatter [kk][item])
    #pragma unroll
    for (int u = 0; u < 4; ++u) {
      ms[(16 * half + 4 * u + 0) * 128 + item] = mv4[u].x;
      ms[(16 * half + 4 * u + 1) * 128 + item] = mv4[u].y;
      ms[(16 * half + 4 * u + 2) * 128 + item] = mv4[u].z;
      ms[(16 * half + 4 * u + 3) * 128 + item] = mv4[u].w;
    }
    __syncthreads();                   // drains q(kt) vmcnt + m ds_writes
    // prefetch next tile (overlaps the FMA compute below)
    if (kt < 15) {
      issue_q(kt + 1, buf ^ 1);
      const int k0n = (kt + 1) * 32;
      #pragma unroll
      for (int u = 0; u < 4; ++u) mv4[u] = *(const float4*)(mrow + k0n + 4 * u);
    }
    // fp32 register-tile GEMM: acc[8][7] += q[8] * m[7], sequential k
    const float* qsb = qs[buf];
    #pragma unroll 2
    for (int kk = 0; kk < 32; ++kk) {
      const float* qr = qsb + kk * 128 + 8 * trg;
      const float* mr = ms + kk * 128 + tc;
      float4 qa = *(const float4*)(qr);
      float4 qb = *(const float4*)(qr + 4);
      float mm[7] = {mr[0], mr[16], mr[32], mr[48], mr[64], mr[80], mr[96]};
      float qq[8] = {qa.x, qa.y, qa.z, qa.w, qb.x, qb.y, qb.z, qb.w};
      #pragma unroll
      for (int r = 0; r < 8; ++r)
        #pragma unroll
        for (int j = 0; j < 7; ++j)
          acc[r][j] = __builtin_fmaf(qq[r], mm[j], acc[r][j]);
    }
    __syncthreads();                   // protect LDS overwrite next iter
    buf ^= 1;
  }

  // ---- in-register softmax + top-10 + renorm per row (16-lane groups) ----
  // FULLY unrolled: all acc/att/id/w indices compile-time constant.
  const int baserow = n0 + 8 * trg;
  #pragma unroll
  for (int r = 0; r < 8; ++r) {
    float attv[KTOP]; int id[KTOP];
    float mx = 0.f, Z = 0.f;
    #pragma unroll
    for (int s = 0; s < KTOP; ++s) {
      float bv = -INFINITY; int bi = 0x7fffffff;
      #pragma unroll
      for (int j = 0; j < 7; ++j) {
        bool valid = (j < 6) || (tc < 4);       // item tc+16j < 100
        float v = valid ? acc[r][j] : -INFINITY;
        if (v > bv) { bv = v; bi = tc + 16 * j; }  // ascending idx: > keeps lowest
      }
      #pragma unroll
      for (int d = 1; d < 16; d <<= 1) {
        float ov = __shfl_xor(bv, d, 16);
        int   oi = __shfl_xor(bi, d, 16);
        if (ov > bv || (ov == bv && oi < bi)) { bv = ov; bi = oi; }
      }
      if (s == 0) {                    // have global max: compute Z on unmasked values
        mx = bv;
        float zp = 0.f;
        #pragma unroll
        for (int j = 0; j < 7; ++j) {
          bool valid = (j < 6) || (tc < 4);
          zp += valid ? __expf(acc[r][j] - mx) : 0.f;
        }
        #pragma unroll
        for (int d = 1; d < 16; d <<= 1) zp += __shfl_xor(zp, d, 16);
        Z = zp;
      }
      attv[s] = bv; id[s] = bi;
      // mask winner (predicated, constant indices)
      #pragma unroll
      for (int j = 0; j < 7; ++j)
        if (bi == tc + 16 * j) acc[r][j] = -INFINITY;
    }
    float invZ = 1.f / Z;
    float p0 = invZ;                   // exp(attv0-mx)=1
    float s2 = 0.f, wv[KTOP];
    #pragma unroll
    for (int s = 0; s < KTOP; ++s) {
      float p = __expf(attv[s] - mx) * invZ;
      float e = __expf(p - p0);
      wv[s] = e; s2 += e;
    }
    float inv2 = 1.f / s2;
    unsigned short wb[KTOP];
    #pragma unroll
    for (int s = 0; s < KTOP; ++s) wb[s] = bf16u(wv[s] * inv2);
    // assemble W row: lane tc owns items 8tc..8tc+7 (one uint4), predicated selects
    unsigned int packed[4];
    #pragma unroll
    for (int q2 = 0; q2 < 4; ++q2) {
      unsigned int lo = 0u, hi = 0u;
      #pragma unroll
      for (int s = 0; s < KTOP; ++s) {
        lo = (id[s] == 8 * tc + 2 * q2)     ? (unsigned int)wb[s] : lo;
        hi = (id[s] == 8 * tc + 2 * q2 + 1) ? (unsigned int)wb[s] : hi;
      }
      packed[q2] = lo | (hi << 16);
    }
    if (tc < 14) {
      uint4 o; o.x = packed[0]; o.y = packed[1]; o.z = packed[2]; o.w = packed[3];
      *(uint4*)(Wd + (size_t)(baserow + r) * 112 + 8 * tc) = o;
    }
  }
}

// ---- K2: out^T = mp^T(bf16) x W^T(bf16) via MFMA; tiles 128c x 128n, K=128 ----
__global__ __launch_bounds__(256, 2) void recon(
    const float* __restrict__ mp, const unsigned short* __restrict__ Wd,
    float* __restrict__ out)
{
  __shared__ unsigned short Ash[128 * 136];  // mp^T bf16 [c][k], k-stride 136
  __shared__ unsigned short Bsh[128 * 136];  // W bf16 [n][k]
  const int t  = threadIdx.x;
  const int ct = blockIdx.x & 3, nt = blockIdx.x >> 2;
  const int c0 = ct * 128, n0 = nt * 128;
  const int b  = n0 >> 12, sp0 = n0 & (HW - 1);

  #pragma unroll
  for (int j = 0; j < 13; ++j) {
    int task = t + 256 * j;
    if (task < 3200) {
      int k = task >> 5, c4 = (task & 31) << 2;
      float4 v = *(const float4*)(mp + (size_t)k * CDIM + c0 + c4);
      Ash[(c4 + 0) * 136 + k] = bf16u(v.x);
      Ash[(c4 + 1) * 136 + k] = bf16u(v.y);
      Ash[(c4 + 2) * 136 + k] = bf16u(v.z);
      Ash[(c4 + 3) * 136 + k] = bf16u(v.w);
    }
  }
  {
    int c = t >> 1, hf = t & 1;
    unsigned int* A32 = (unsigned int*)Ash;
    #pragma unroll
    for (int j = 0; j < 9; ++j) { int k = 100 + 2 * (hf * 9 + j); A32[(c * 136 + k) >> 1] = 0u; }
  }
  {
    int n = t >> 1, hf = t & 1;
    #pragma unroll
    for (int j = 0; j < 7; ++j) {
      int f = hf * 7 + j;
      *(bf16x8*)(Bsh + n * 136 + 8 * f) = *(const bf16x8*)(Wd + (size_t)(n0 + n) * 112 + 8 * f);
    }
    unsigned int* B32 = (unsigned int*)Bsh;
    #pragma unroll
    for (int j = 0; j < 6; ++j) { int k = 112 + 2 * (hf * 6 + j); B32[(n * 136 + k) >> 1] = 0u; }
  }
  __syncthreads();

  const int w = t >> 6, l = t & 63;
  const int arow = l & 15, kg = l >> 4;
  f32x4 acc[2][8];
  #pragma unroll
  for (int cr = 0; cr < 2; ++cr)
    #pragma unroll
    for (int n = 0; n < 8; ++n) acc[cr][n] = (f32x4){0.f, 0.f, 0.f, 0.f};

  #pragma unroll
  for (int ks = 0; ks < 4; ++ks) {
    bf16x8 a0 = *(bf16x8*)(Ash + ((2 * w + 0) * 16 + arow) * 136 + ks * 32 + kg * 8);
    bf16x8 a1 = *(bf16x8*)(Ash + ((2 * w + 1) * 16 + arow) * 136 + ks * 32 + kg * 8);
    #pragma unroll
    for (int nn = 0; nn < 8; ++nn) {
      bf16x8 bb = *(bf16x8*)(Bsh + (nn * 16 + arow) * 136 + ks * 32 + kg * 8);
      acc[0][nn] = __builtin_amdgcn_mfma_f32_16x16x32_bf16(a0, bb, acc[0][nn], 0, 0, 0);
      acc[1][nn] = __builtin_amdgcn_mfma_f32_16x16x32_bf16(a1, bb, acc[1][nn], 0, 0, 0);
    }
  }

  float* ob = out + (size_t)b * CDIM * HW + sp0;
  #pragma unroll
  for (int cr = 0; cr < 2; ++cr) {
    #pragma unroll
    for (int nn = 0; nn < 8; ++nn) {
      int ncol = nn * 16 + arow;
      #pragma unroll
      for (int j = 0; j < 4; ++j) {
        int cc = c0 + (2 * w + cr) * 16 + kg * 4 + j;
        ob[(size_t)cc * HW + ncol] = acc[cr][nn][j];
      }
    }
  }
}

// ---- loss: mean |0.5 * off-diag gram| ----
__global__ void loss_partial(const float* __restrict__ mp, float* __restrict__ part)
{
  __shared__ float mi[CDIM];
  __shared__ float red[4];
  const int i = blockIdx.x;
  const int t = threadIdx.x;
  for (int k = t; k < CDIM; k += 256) mi[k] = mp[i * CDIM + k];
  __syncthreads();
  float v = 0.f;
  if (t < NITEM && t != i) {
    const float* mj = mp + t * CDIM;
    float d = 0.f;
    #pragma unroll 8
    for (int k = 0; k < CDIM; ++k) d += mi[k] * mj[k];
    v = fabsf(0.5f * d);
  }
  #pragma unroll
  for (int o = 32; o > 0; o >>= 1) v += __shfl_down(v, o, 64);
  if ((t & 63) == 0) red[t >> 6] = v;
  __syncthreads();
  if (t == 0) part[i] = red[0] + red[1] + red[2] + red[3];
}

__global__ void loss_final(const float* __restrict__ part, float* __restrict__ out_loss)
{
  if (threadIdx.x == 0) {
    float s = 0.f;
    for (int i = 0; i < NITEM; ++i) s += part[i];
    *out_loss = s / (float)(NITEM * NITEM);
  }
}

extern "C" void kernel_launch(void* const* d_in, const int* in_sizes, int n_in,
                              void* d_out, int out_size, void* d_ws, size_t ws_size,
                              hipStream_t stream) {
  const float* x  = (const float*)d_in[0];
  const float* mp = (const float*)d_in[1];
  float* out = (float*)d_out;
  unsigned short* Wd = (unsigned short*)d_ws;                    // 131072*112*2 = 29.36 MB
  float* part = (float*)((char*)d_ws + (size_t)131072 * 112 * 2);

  logits_topk<<<1024, 256, 0, stream>>>(x, mp, Wd);
  recon<<<4096, 256, 0, stream>>>(mp, Wd, out);
  loss_partial<<<NITEM, 256, 0, stream>>>(mp, part);
  loss_final<<<1, 64, 0, stream>>>(part, out + (out_size - 1));
}

// Round 13
// 363.886 us; speedup vs baseline: 2.6584x; 1.0281x over previous
//
#include <hip/hip_runtime.h>
#include <math.h>

#define NITEM 100
#define CDIM 512
#define HW 4096
#define KTOP 10

typedef __attribute__((ext_vector_type(8))) short bf16x8;
typedef __attribute__((ext_vector_type(4))) float f32x4;
typedef __attribute__((ext_vector_type(2))) float f32x2;

__device__ inline unsigned short bf16u(float f) {
  unsigned int u = __float_as_uint(f);
  u += 0x7fffu + ((u >> 16) & 1u);     // RNE
  return (unsigned short)(u >> 16);
}

#if __has_builtin(__builtin_elementwise_fma)
__device__ inline f32x2 pkfma(f32x2 a, f32x2 b, f32x2 c) {
  return __builtin_elementwise_fma(a, b, c);   // -> v_pk_fma_f32 on gfx950
}
#else
__device__ inline f32x2 pkfma(f32x2 a, f32x2 b, f32x2 c) {
  f32x2 r; r.x = __builtin_fmaf(a.x, b.x, c.x); r.y = __builtin_fmaf(a.y, b.y, c.y);
  return r;                                     // identical IEEE FMA semantics
}
#endif

// ---- K1: fp32 logits GEMM + in-register top-10 + renorm -> dense bf16 W [N][112] ----
// R12/R6 structure byte-for-byte EXCEPT the inner FMA is paired across rows via
// v_pk_fma_f32 (2 FMAs/instr): acc2[p][j].x = row 2p, .y = row 2p+1. Each row's
// logit is still the same sequential-k IEEE FMA chain -> bit-identical selection.
// 256 threads, 128 rows/block. Thread (trg=t>>4, tc=t&15): rows 8trg..8trg+7,
// items tc+16j (j=0..6). q via global_load_lds (dbuf); m reg-staged scatter.
// amdgpu_waves_per_eu(3,3): proven spill-free mode; acc stays 56 floats.
__global__ __launch_bounds__(256) __attribute__((amdgpu_waves_per_eu(3, 3)))
void logits_topk(
    const float* __restrict__ x, const float* __restrict__ mp,
    unsigned short* __restrict__ Wd)
{
  __shared__ float qs[2][32 * 128];   // [buf][kk][row]  2 x 16 KB
  __shared__ float ms[32 * 128];      // [kk][item]      16 KB

  const int t   = threadIdx.x;
  const int tc  = t & 15;
  const int trg = t >> 4;              // 0..15
  const int n0  = blockIdx.x * 128;
  const int b   = n0 >> 12;
  const int sp0 = n0 & (HW - 1);
  const float* xb = x + (size_t)b * CDIM * HW + sp0;

  const int w = t >> 6, l = t & 63;    // wave id, lane id
  const int item = t & 127;
  const int half = t >> 7;             // kk range 16*half..16*half+15
  const float* mrow = mp + (size_t)(item < NITEM ? item : 0) * CDIM + 16 * half;

  // q tile load: wave w covers kk = 8w..8w+7; per instr i: kk = 8w+2i+(l>>5), row = (l&31)*4
  auto issue_q = [&](int kt, int buf) {
    const int k0 = kt * 32;
    #pragma unroll
    for (int i = 0; i < 4; ++i) {
      const float* src = xb + (size_t)(k0 + 8 * w + 2 * i + (l >> 5)) * HW + (l & 31) * 4;
      float* dst = &qs[buf][(8 * w + 2 * i) * 128];        // wave-uniform base
      __builtin_amdgcn_global_load_lds(
          (const __attribute__((address_space(1))) void*)src,
          (__attribute__((address_space(3))) void*)dst, 16, 0, 0);
    }
  };

  f32x2 acc2[4][7];                    // 28 pairs = 56 floats (no-spill envelope)
  #pragma unroll
  for (int p = 0; p < 4; ++p)
    #pragma unroll
    for (int j = 0; j < 7; ++j) acc2[p][j] = (f32x2){0.f, 0.f};

  // prologue: tile 0
  issue_q(0, 0);
  float4 mv4[4];
  #pragma unroll
  for (int u = 0; u < 4; ++u) mv4[u] = *(const float4*)(mrow + 4 * u);

  int buf = 0;
  #pragma unroll 1
  for (int kt = 0; kt < 16; ++kt) {
    // store staged m registers -> LDS (scatter [kk][item])
    #pragma unroll
    for (int u = 0; u < 4; ++u) {
      ms[(16 * half + 4 * u + 0) * 128 + item] = mv4[u].x;
      ms[(16 * half + 4 * u + 1) * 128 + item] = mv4[u].y;
      ms[(16 * half + 4 * u + 2) * 128 + item] = mv4[u].z;
      ms[(16 * half + 4 * u + 3) * 128 + item] = mv4[u].w;
    }
    __syncthreads();                   // drains q(kt) vmcnt + m ds_writes
    // prefetch next tile (overlaps the FMA compute below)
    if (kt < 15) {
      issue_q(kt + 1, buf ^ 1);
      const int k0n = (kt + 1) * 32;
      #pragma unroll
      for (int u = 0; u < 4; ++u) mv4[u] = *(const float4*)(mrow + k0n + 4 * u);
    }
    // fp32 register-tile GEMM: acc2[4][7] (row-pairs) += q[8] * m[7], sequential k
    const float* qsb = qs[buf];
    #pragma unroll 2
    for (int kk = 0; kk < 32; ++kk) {
      const float* qr = qsb + kk * 128 + 8 * trg;
      const float* mr = ms + kk * 128 + tc;
      float4 qa = *(const float4*)(qr);
      float4 qb = *(const float4*)(qr + 4);
      float mm[7] = {mr[0], mr[16], mr[32], mr[48], mr[64], mr[80], mr[96]};
      f32x2 qp[4] = {(f32x2){qa.x, qa.y}, (f32x2){qa.z, qa.w},
                     (f32x2){qb.x, qb.y}, (f32x2){qb.z, qb.w}};
      #pragma unroll
      for (int j = 0; j < 7; ++j) {
        f32x2 md = (f32x2){mm[j], mm[j]};
        #pragma unroll
        for (int p = 0; p < 4; ++p)
          acc2[p][j] = pkfma(qp[p], md, acc2[p][j]);
      }
    }
    __syncthreads();                   // protect LDS overwrite next iter
    buf ^= 1;
  }

  // ---- in-register softmax + top-10 + renorm per row (16-lane groups) ----
  // FULLY unrolled: all register indices / vector components compile-time constant.
  const int baserow = n0 + 8 * trg;
  #pragma unroll
  for (int r = 0; r < 8; ++r) {
    float attv[KTOP]; int id[KTOP];
    float mx = 0.f, Z = 0.f;
    #pragma unroll
    for (int s = 0; s < KTOP; ++s) {
      float bv = -INFINITY; int bi = 0x7fffffff;
      #pragma unroll
      for (int j = 0; j < 7; ++j) {
        bool valid = (j < 6) || (tc < 4);       // item tc+16j < 100
        float av = (r & 1) ? acc2[r >> 1][j].y : acc2[r >> 1][j].x;
        float v = valid ? av : -INFINITY;
        if (v > bv) { bv = v; bi = tc + 16 * j; }  // ascending idx: > keeps lowest
      }
      #pragma unroll
      for (int d = 1; d < 16; d <<= 1) {
        float ov = __shfl_xor(bv, d, 16);
        int   oi = __shfl_xor(bi, d, 16);
        if (ov > bv || (ov == bv && oi < bi)) { bv = ov; bi = oi; }
      }
      if (s == 0) {                    // have global max: compute Z on unmasked values
        mx = bv;
        float zp = 0.f;
        #pragma unroll
        for (int j = 0; j < 7; ++j) {
          bool valid = (j < 6) || (tc < 4);
          float av = (r & 1) ? acc2[r >> 1][j].y : acc2[r >> 1][j].x;
          zp += valid ? __expf(av - mx) : 0.f;
        }
        #pragma unroll
        for (int d = 1; d < 16; d <<= 1) zp += __shfl_xor(zp, d, 16);
        Z = zp;
      }
      attv[s] = bv; id[s] = bi;
      // mask winner (predicated, constant indices/components)
      #pragma unroll
      for (int j = 0; j < 7; ++j)
        if (bi == tc + 16 * j) {
          if (r & 1) acc2[r >> 1][j].y = -INFINITY;
          else       acc2[r >> 1][j].x = -INFINITY;
        }
    }
    float invZ = 1.f / Z;
    float p0 = invZ;                   // exp(attv0-mx)=1
    float s2 = 0.f, wv[KTOP];
    #pragma unroll
    for (int s = 0; s < KTOP; ++s) {
      float p = __expf(attv[s] - mx) * invZ;
      float e = __expf(p - p0);
      wv[s] = e; s2 += e;
    }
    float inv2 = 1.f / s2;
    unsigned short wb[KTOP];
    #pragma unroll
    for (int s = 0; s < KTOP; ++s) wb[s] = bf16u(wv[s] * inv2);
    // assemble W row: lane tc owns items 8tc..8tc+7 (one uint4), predicated selects
    unsigned int packed[4];
    #pragma unroll
    for (int q2 = 0; q2 < 4; ++q2) {
      unsigned int lo = 0u, hi = 0u;
      #pragma unroll
      for (int s = 0; s < KTOP; ++s) {
        lo = (id[s] == 8 * tc + 2 * q2)     ? (unsigned int)wb[s] : lo;
        hi = (id[s] == 8 * tc + 2 * q2 + 1) ? (unsigned int)wb[s] : hi;
      }
      packed[q2] = lo | (hi << 16);
    }
    if (tc < 14) {
      uint4 o; o.x = packed[0]; o.y = packed[1]; o.z = packed[2]; o.w = packed[3];
      *(uint4*)(Wd + (size_t)(baserow + r) * 112 + 8 * tc) = o;
    }
  }
}

// ---- K2: out^T = mp^T(bf16) x W^T(bf16) via MFMA; tiles 128c x 128n, K=128 ----
__global__ __launch_bounds__(256, 2) void recon(
    const float* __restrict__ mp, const unsigned short* __restrict__ Wd,
    float* __restrict__ out)
{
  __shared__ unsigned short Ash[128 * 136];  // mp^T bf16 [c][k], k-stride 136
  __shared__ unsigned short Bsh[128 * 136];  // W bf16 [n][k]
  const int t  = threadIdx.x;
  const int ct = blockIdx.x & 3, nt = blockIdx.x >> 2;
  const int c0 = ct * 128, n0 = nt * 128;
  const int b  = n0 >> 12, sp0 = n0 & (HW - 1);

  #pragma unroll
  for (int j = 0; j < 13; ++j) {
    int task = t + 256 * j;
    if (task < 3200) {
      int k = task >> 5, c4 = (task & 31) << 2;
      float4 v = *(const float4*)(mp + (size_t)k * CDIM + c0 + c4);
      Ash[(c4 + 0) * 136 + k] = bf16u(v.x);
      Ash[(c4 + 1) * 136 + k] = bf16u(v.y);
      Ash[(c4 + 2) * 136 + k] = bf16u(v.z);
      Ash[(c4 + 3) * 136 + k] = bf16u(v.w);
    }
  }
  {
    int c = t >> 1, hf = t & 1;
    unsigned int* A32 = (unsigned int*)Ash;
    #pragma unroll
    for (int j = 0; j < 9; ++j) { int k = 100 + 2 * (hf * 9 + j); A32[(c * 136 + k) >> 1] = 0u; }
  }
  {
    int n = t >> 1, hf = t & 1;
    #pragma unroll
    for (int j = 0; j < 7; ++j) {
      int f = hf * 7 + j;
      *(bf16x8*)(Bsh + n * 136 + 8 * f) = *(const bf16x8*)(Wd + (size_t)(n0 + n) * 112 + 8 * f);
    }
    unsigned int* B32 = (unsigned int*)Bsh;
    #pragma unroll
    for (int j = 0; j < 6; ++j) { int k = 112 + 2 * (hf * 6 + j); B32[(n * 136 + k) >> 1] = 0u; }
  }
  __syncthreads();

  const int w = t >> 6, l = t & 63;
  const int arow = l & 15, kg = l >> 4;
  f32x4 acc[2][8];
  #pragma unroll
  for (int cr = 0; cr < 2; ++cr)
    #pragma unroll
    for (int n = 0; n < 8; ++n) acc[cr][n] = (f32x4){0.f, 0.f, 0.f, 0.f};

  #pragma unroll
  for (int ks = 0; ks < 4; ++ks) {
    bf16x8 a0 = *(bf16x8*)(Ash + ((2 * w + 0) * 16 + arow) * 136 + ks * 32 + kg * 8);
    bf16x8 a1 = *(bf16x8*)(Ash + ((2 * w + 1) * 16 + arow) * 136 + ks * 32 + kg * 8);
    #pragma unroll
    for (int nn = 0; nn < 8; ++nn) {
      bf16x8 bb = *(bf16x8*)(Bsh + (nn * 16 + arow) * 136 + ks * 32 + kg * 8);
      acc[0][nn] = __builtin_amdgcn_mfma_f32_16x16x32_bf16(a0, bb, acc[0][nn], 0, 0, 0);
      acc[1][nn] = __builtin_amdgcn_mfma_f32_16x16x32_bf16(a1, bb, acc[1][nn], 0, 0, 0);
    }
  }

  float* ob = out + (size_t)b * CDIM * HW + sp0;
  #pragma unroll
  for (int cr = 0; cr < 2; ++cr) {
    #pragma unroll
    for (int nn = 0; nn < 8; ++nn) {
      int ncol = nn * 16 + arow;
      #pragma unroll
      for (int j = 0; j < 4; ++j) {
        int cc = c0 + (2 * w + cr) * 16 + kg * 4 + j;
        ob[(size_t)cc * HW + ncol] = acc[cr][nn][j];
      }
    }
  }
}

// ---- loss: mean |0.5 * off-diag gram| ----
__global__ void loss_partial(const float* __restrict__ mp, float* __restrict__ part)
{
  __shared__ float mi[CDIM];
  __shared__ float red[4];
  const int i = blockIdx.x;
  const int t = threadIdx.x;
  for (int k = t; k < CDIM; k += 256) mi[k] = mp[i * CDIM + k];
  __syncthreads();
  float v = 0.f;
  if (t < NITEM && t != i) {
    const float* mj = mp + t * CDIM;
    float d = 0.f;
    #pragma unroll 8
    for (int k = 0; k < CDIM; ++k) d += mi[k] * mj[k];
    v = fabsf(0.5f * d);
  }
  #pragma unroll
  for (int o = 32; o > 0; o >>= 1) v += __shfl_down(v, o, 64);
  if ((t & 63) == 0) red[t >> 6] = v;
  __syncthreads();
  if (t == 0) part[i] = red[0] + red[1] + red[2] + red[3];
}

__global__ void loss_final(const float* __restrict__ part, float* __restrict__ out_loss)
{
  if (threadIdx.x == 0) {
    float s = 0.f;
    for (int i = 0; i < NITEM; ++i) s += part[i];
    *out_loss = s / (float)(NITEM * NITEM);
  }
}

extern "C" void kernel_launch(void* const* d_in, const int* in_sizes, int n_in,
                              void* d_out, int out_size, void* d_ws, size_t ws_size,
                              hipStream_t stream) {
  const float* x  = (const float*)d_in[0];
  const float* mp = (const float*)d_in[1];
  float* out = (float*)d_out;
  unsigned short* Wd = (unsigned short*)d_ws;                    // 131072*112*2 = 29.36 MB
  float* part = (float*)((char*)d_ws + (size_t)131072 * 112 * 2);

  logits_topk<<<1024, 256, 0, stream>>>(x, mp, Wd);
  recon<<<4096, 256, 0, stream>>>(mp, Wd, out);
  loss_partial<<<NITEM, 256, 0, stream>>>(mp, part);
  loss_final<<<1, 64, 0, stream>>>(part, out + (out_size - 1));
}

// Round 14
// 357.502 us; speedup vs baseline: 2.7059x; 1.0179x over previous
//
#include <hip/hip_runtime.h>
#include <math.h>

#define NITEM 100
#define CDIM 512
#define HW 4096
#define KTOP 10

typedef __attribute__((ext_vector_type(8))) short bf16x8;
typedef __attribute__((ext_vector_type(4))) float f32x4;
typedef __attribute__((ext_vector_type(2))) float f32x2;

__device__ inline unsigned short bf16u(float f) {
  unsigned int u = __float_as_uint(f);
  u += 0x7fffu + ((u >> 16) & 1u);     // RNE
  return (unsigned short)(u >> 16);
}

#if __has_builtin(__builtin_elementwise_fma)
__device__ inline f32x2 pkfma(f32x2 a, f32x2 b, f32x2 c) {
  return __builtin_elementwise_fma(a, b, c);   // -> v_pk_fma_f32 on gfx950
}
#else
__device__ inline f32x2 pkfma(f32x2 a, f32x2 b, f32x2 c) {
  f32x2 r; r.x = __builtin_fmaf(a.x, b.x, c.x); r.y = __builtin_fmaf(a.y, b.y, c.y);
  return r;                                     // identical IEEE FMA semantics
}
#endif

#define MSTR 34   // ms row stride: 32 kk + 2 pad (even -> conflict-free b64 reads)

// ---- K1: fp32 logits GEMM + in-register top-10 + renorm -> dense bf16 W [N][112] ----
// R13 structure with the m tile TRANSPOSED to [item][kk] (stride 34):
//  - m read: one ds_read_b64 serves TWO kk's (3.5 LDS instr/kk vs 7)
//  - m staging: 8 contiguous ds_write_b64 (vs 16 scatter b32)
// FMA order per (row,item) unchanged (kk ascending) -> bit-identical logits.
// 256 threads, 128 rows/block; thread (trg=t>>4, tc=t&15): rows 8trg..8trg+7,
// items tc+16j. q via global_load_lds dbuf. waves_per_eu(3,3) spill-free mode.
__global__ __launch_bounds__(256) __attribute__((amdgpu_waves_per_eu(3, 3)))
void logits_topk(
    const float* __restrict__ x, const float* __restrict__ mp,
    unsigned short* __restrict__ Wd)
{
  __shared__ float qs[2][32 * 128];    // [buf][kk][row]  2 x 16 KB
  __shared__ float ms[128 * MSTR];     // [item][kk]      17 KB

  const int t   = threadIdx.x;
  const int tc  = t & 15;
  const int trg = t >> 4;              // 0..15
  const int n0  = blockIdx.x * 128;
  const int b   = n0 >> 12;
  const int sp0 = n0 & (HW - 1);
  const float* xb = x + (size_t)b * CDIM * HW + sp0;

  const int w = t >> 6, l = t & 63;    // wave id, lane id
  const int item = t & 127;
  const int half = t >> 7;             // k sub-range 16*half..16*half+15
  const float* mrow = mp + (size_t)(item < NITEM ? item : 0) * CDIM + 16 * half;

  // q tile load: wave w covers kk = 8w..8w+7; per instr i: kk = 8w+2i+(l>>5), row = (l&31)*4
  auto issue_q = [&](int kt, int buf) {
    const int k0 = kt * 32;
    #pragma unroll
    for (int i = 0; i < 4; ++i) {
      const float* src = xb + (size_t)(k0 + 8 * w + 2 * i + (l >> 5)) * HW + (l & 31) * 4;
      float* dst = &qs[buf][(8 * w + 2 * i) * 128];        // wave-uniform base
      __builtin_amdgcn_global_load_lds(
          (const __attribute__((address_space(1))) void*)src,
          (__attribute__((address_space(3))) void*)dst, 16, 0, 0);
    }
  };

  f32x2 acc2[4][7];                    // 28 pairs = 56 floats (no-spill envelope)
  #pragma unroll
  for (int p = 0; p < 4; ++p)
    #pragma unroll
    for (int j = 0; j < 7; ++j) acc2[p][j] = (f32x2){0.f, 0.f};

  // prologue: tile 0
  issue_q(0, 0);
  float4 mv4[4];
  #pragma unroll
  for (int u = 0; u < 4; ++u) mv4[u] = *(const float4*)(mrow + 4 * u);

  int buf = 0;
  #pragma unroll 1
  for (int kt = 0; kt < 16; ++kt) {
    // store staged m registers -> LDS row [item][16*half .. +15] (contiguous b64s)
    {
      float* dstm = ms + item * MSTR + 16 * half;
      #pragma unroll
      for (int u = 0; u < 4; ++u) {
        *(f32x2*)(dstm + 4 * u)     = (f32x2){mv4[u].x, mv4[u].y};
        *(f32x2*)(dstm + 4 * u + 2) = (f32x2){mv4[u].z, mv4[u].w};
      }
    }
    __syncthreads();                   // drains q(kt) vmcnt + m ds_writes
    // prefetch next tile (overlaps the FMA compute below)
    if (kt < 15) {
      issue_q(kt + 1, buf ^ 1);
      const int k0n = (kt + 1) * 32;
      #pragma unroll
      for (int u = 0; u < 4; ++u) mv4[u] = *(const float4*)(mrow + k0n + 4 * u);
    }
    // fp32 register-tile GEMM: acc2[4][7] (row-pairs) += q[8] * m[7]
    // kk = 2*kk2 + kkd ascending -> identical sequential-k FMA chain per logit
    const float* qsb = qs[buf];
    #pragma unroll 2
    for (int kk2 = 0; kk2 < 16; ++kk2) {
      f32x2 mm2[7];
      #pragma unroll
      for (int j = 0; j < 7; ++j)
        mm2[j] = *(const f32x2*)(ms + (tc + 16 * j) * MSTR + 2 * kk2);
      #pragma unroll
      for (int kkd = 0; kkd < 2; ++kkd) {
        const float* qr = qsb + (2 * kk2 + kkd) * 128 + 8 * trg;
        float4 qa = *(const float4*)(qr);
        float4 qb = *(const float4*)(qr + 4);
        f32x2 qp[4] = {(f32x2){qa.x, qa.y}, (f32x2){qa.z, qa.w},
                       (f32x2){qb.x, qb.y}, (f32x2){qb.z, qb.w}};
        #pragma unroll
        for (int j = 0; j < 7; ++j) {
          float mk = kkd ? mm2[j].y : mm2[j].x;
          f32x2 md = (f32x2){mk, mk};
          #pragma unroll
          for (int p = 0; p < 4; ++p)
            acc2[p][j] = pkfma(qp[p], md, acc2[p][j]);
        }
      }
    }
    __syncthreads();                   // protect ms/qs overwrite next iter
    buf ^= 1;
  }

  // ---- in-register softmax + top-10 + renorm per row (16-lane groups) ----
  // FULLY unrolled: all register indices / vector components compile-time constant.
  const int baserow = n0 + 8 * trg;
  #pragma unroll
  for (int r = 0; r < 8; ++r) {
    float attv[KTOP]; int id[KTOP];
    float mx = 0.f, Z = 0.f;
    #pragma unroll
    for (int s = 0; s < KTOP; ++s) {
      float bv = -INFINITY; int bi = 0x7fffffff;
      #pragma unroll
      for (int j = 0; j < 7; ++j) {
        bool valid = (j < 6) || (tc < 4);       // item tc+16j < 100
        float av = (r & 1) ? acc2[r >> 1][j].y : acc2[r >> 1][j].x;
        float v = valid ? av : -INFINITY;
        if (v > bv) { bv = v; bi = tc + 16 * j; }  // ascending idx: > keeps lowest
      }
      #pragma unroll
      for (int d = 1; d < 16; d <<= 1) {
        float ov = __shfl_xor(bv, d, 16);
        int   oi = __shfl_xor(bi, d, 16);
        if (ov > bv || (ov == bv && oi < bi)) { bv = ov; bi = oi; }
      }
      if (s == 0) {                    // have global max: compute Z on unmasked values
        mx = bv;
        float zp = 0.f;
        #pragma unroll
        for (int j = 0; j < 7; ++j) {
          bool valid = (j < 6) || (tc < 4);
          float av = (r & 1) ? acc2[r >> 1][j].y : acc2[r >> 1][j].x;
          zp += valid ? __expf(av - mx) : 0.f;
        }
        #pragma unroll
        for (int d = 1; d < 16; d <<= 1) zp += __shfl_xor(zp, d, 16);
        Z = zp;
      }
      attv[s] = bv; id[s] = bi;
      // mask winner (predicated, constant indices/components)
      #pragma unroll
      for (int j = 0; j < 7; ++j)
        if (bi == tc + 16 * j) {
          if (r & 1) acc2[r >> 1][j].y = -INFINITY;
          else       acc2[r >> 1][j].x = -INFINITY;
        }
    }
    float invZ = 1.f / Z;
    float p0 = invZ;                   // exp(attv0-mx)=1
    float s2 = 0.f, wv[KTOP];
    #pragma unroll
    for (int s = 0; s < KTOP; ++s) {
      float p = __expf(attv[s] - mx) * invZ;
      float e = __expf(p - p0);
      wv[s] = e; s2 += e;
    }
    float inv2 = 1.f / s2;
    unsigned short wb[KTOP];
    #pragma unroll
    for (int s = 0; s < KTOP; ++s) wb[s] = bf16u(wv[s] * inv2);
    // assemble W row: lane tc owns items 8tc..8tc+7 (one uint4), predicated selects
    unsigned int packed[4];
    #pragma unroll
    for (int q2 = 0; q2 < 4; ++q2) {
      unsigned int lo = 0u, hi = 0u;
      #pragma unroll
      for (int s = 0; s < KTOP; ++s) {
        lo = (id[s] == 8 * tc + 2 * q2)     ? (unsigned int)wb[s] : lo;
        hi = (id[s] == 8 * tc + 2 * q2 + 1) ? (unsigned int)wb[s] : hi;
      }
      packed[q2] = lo | (hi << 16);
    }
    if (tc < 14) {
      uint4 o; o.x = packed[0]; o.y = packed[1]; o.z = packed[2]; o.w = packed[3];
      *(uint4*)(Wd + (size_t)(baserow + r) * 112 + 8 * tc) = o;
    }
  }
}

// ---- K2: out^T = mp^T(bf16) x W^T(bf16) via MFMA; tiles 128c x 128n, K=128 ----
__global__ __launch_bounds__(256, 2) void recon(
    const float* __restrict__ mp, const unsigned short* __restrict__ Wd,
    float* __restrict__ out)
{
  __shared__ unsigned short Ash[128 * 136];  // mp^T bf16 [c][k], k-stride 136
  __shared__ unsigned short Bsh[128 * 136];  // W bf16 [n][k]
  const int t  = threadIdx.x;
  const int ct = blockIdx.x & 3, nt = blockIdx.x >> 2;
  const int c0 = ct * 128, n0 = nt * 128;
  const int b  = n0 >> 12, sp0 = n0 & (HW - 1);

  #pragma unroll
  for (int j = 0; j < 13; ++j) {
    int task = t + 256 * j;
    if (task < 3200) {
      int k = task >> 5, c4 = (task & 31) << 2;
      float4 v = *(const float4*)(mp + (size_t)k * CDIM + c0 + c4);
      Ash[(c4 + 0) * 136 + k] = bf16u(v.x);
      Ash[(c4 + 1) * 136 + k] = bf16u(v.y);
      Ash[(c4 + 2) * 136 + k] = bf16u(v.z);
      Ash[(c4 + 3) * 136 + k] = bf16u(v.w);
    }
  }
  {
    int c = t >> 1, hf = t & 1;
    unsigned int* A32 = (unsigned int*)Ash;
    #pragma unroll
    for (int j = 0; j < 9; ++j) { int k = 100 + 2 * (hf * 9 + j); A32[(c * 136 + k) >> 1] = 0u; }
  }
  {
    int n = t >> 1, hf = t & 1;
    #pragma unroll
    for (int j = 0; j < 7; ++j) {
      int f = hf * 7 + j;
      *(bf16x8*)(Bsh + n * 136 + 8 * f) = *(const bf16x8*)(Wd + (size_t)(n0 + n) * 112 + 8 * f);
    }
    unsigned int* B32 = (unsigned int*)Bsh;
    #pragma unroll
    for (int j = 0; j < 6; ++j) { int k = 112 + 2 * (hf * 6 + j); B32[(n * 136 + k) >> 1] = 0u; }
  }
  __syncthreads();

  const int w = t >> 6, l = t & 63;
  const int arow = l & 15, kg = l >> 4;
  f32x4 acc[2][8];
  #pragma unroll
  for (int cr = 0; cr < 2; ++cr)
    #pragma unroll
    for (int n = 0; n < 8; ++n) acc[cr][n] = (f32x4){0.f, 0.f, 0.f, 0.f};

  #pragma unroll
  for (int ks = 0; ks < 4; ++ks) {
    bf16x8 a0 = *(bf16x8*)(Ash + ((2 * w + 0) * 16 + arow) * 136 + ks * 32 + kg * 8);
    bf16x8 a1 = *(bf16x8*)(Ash + ((2 * w + 1) * 16 + arow) * 136 + ks * 32 + kg * 8);
    #pragma unroll
    for (int nn = 0; nn < 8; ++nn) {
      bf16x8 bb = *(bf16x8*)(Bsh + (nn * 16 + arow) * 136 + ks * 32 + kg * 8);
      acc[0][nn] = __builtin_amdgcn_mfma_f32_16x16x32_bf16(a0, bb, acc[0][nn], 0, 0, 0);
      acc[1][nn] = __builtin_amdgcn_mfma_f32_16x16x32_bf16(a1, bb, acc[1][nn], 0, 0, 0);
    }
  }

  float* ob = out + (size_t)b * CDIM * HW + sp0;
  #pragma unroll
  for (int cr = 0; cr < 2; ++cr) {
    #pragma unroll
    for (int nn = 0; nn < 8; ++nn) {
      int ncol = nn * 16 + arow;
      #pragma unroll
      for (int j = 0; j < 4; ++j) {
        int cc = c0 + (2 * w + cr) * 16 + kg * 4 + j;
        ob[(size_t)cc * HW + ncol] = acc[cr][nn][j];
      }
    }
  }
}

// ---- loss: mean |0.5 * off-diag gram| ----
__global__ void loss_partial(const float* __restrict__ mp, float* __restrict__ part)
{
  __shared__ float mi[CDIM];
  __shared__ float red[4];
  const int i = blockIdx.x;
  const int t = threadIdx.x;
  for (int k = t; k < CDIM; k += 256) mi[k] = mp[i * CDIM + k];
  __syncthreads();
  float v = 0.f;
  if (t < NITEM && t != i) {
    const float* mj = mp + t * CDIM;
    float d = 0.f;
    #pragma unroll 8
    for (int k = 0; k < CDIM; ++k) d += mi[k] * mj[k];
    v = fabsf(0.5f * d);
  }
  #pragma unroll
  for (int o = 32; o > 0; o >>= 1) v += __shfl_down(v, o, 64);
  if ((t & 63) == 0) red[t >> 6] = v;
  __syncthreads();
  if (t == 0) part[i] = red[0] + red[1] + red[2] + red[3];
}

__global__ void loss_final(const float* __restrict__ part, float* __restrict__ out_loss)
{
  if (threadIdx.x == 0) {
    float s = 0.f;
    for (int i = 0; i < NITEM; ++i) s += part[i];
    *out_loss = s / (float)(NITEM * NITEM);
  }
}

extern "C" void kernel_launch(void* const* d_in, const int* in_sizes, int n_in,
                              void* d_out, int out_size, void* d_ws, size_t ws_size,
                              hipStream_t stream) {
  const float* x  = (const float*)d_in[0];
  const float* mp = (const float*)d_in[1];
  float* out = (float*)d_out;
  unsigned short* Wd = (unsigned short*)d_ws;                    // 131072*112*2 = 29.36 MB
  float* part = (float*)((char*)d_ws + (size_t)131072 * 112 * 2);

  logits_topk<<<1024, 256, 0, stream>>>(x, mp, Wd);
  recon<<<4096, 256, 0, stream>>>(mp, Wd, out);
  loss_partial<<<NITEM, 256, 0, stream>>>(mp, part);
  loss_final<<<1, 64, 0, stream>>>(part, out + (out_size - 1));
}